// Round 3
// baseline (83.005 us; speedup 1.0000x reference)
//
#include <hip/hip_runtime.h>
#include <hip/hip_bf16.h>

// out[b, c, m] = weight[idx[b, m], c]   b<256, c<1024, m<64  (fp32, 64 MiB out)
//
// Pipelined multi-tile variant:
//  - block = (batch b, 256-channel group). grid = 256*4 = 1024 = 4 blocks/CU
//    exactly (LDS-capped: 2 x 16.3 KiB double buffer) -> single dispatch
//    round, no tail.
//  - Each block processes 4 tiles of 64 channels, double-buffered in LDS:
//      iter ti: issue gathers for tile ti+1 -> store tile ti from LDS ->
//               LDS-write tile ti+1 into the other buffer -> ONE barrier.
//    Gather latency (~200-900 cyc) hides under the store burst; idx loaded
//    once per 4 tiles; 1 barrier/tile instead of 2. Theory: previous
//    version (~35 us kernel, 1.9 TB/s effective vs 5.9 TB/s for the
//    harness fill) was latency/bubble-bound per block, not BW-bound
//    (nt-store experiment falsified the L2-thrash theory).
//  - LDS tile stored transposed [cc][m], PAD=65: both scalar phases are
//    2 lanes/bank = conflict-free (m136). PAD=68 (for b128 reads) would be
//    8-way in the write phase - keep 65 + scalar reads.
//  - Stores remain non-temporal (neutral but theoretically sound;
//    needs native vector type, hence ext_vector_type).

#define BS    256
#define M     64
#define C     1024
#define PAD   65
#define TILES 4

typedef float fx4 __attribute__((ext_vector_type(4)));

__global__ __launch_bounds__(256) void gather_transpose_kernel(
    const int* __restrict__ idx,      // [BS*M] int32
    const float* __restrict__ w,      // [NUM_EMB, C] fp32
    float* __restrict__ out)          // [BS, C, 8, 8] fp32
{
    const int b      = blockIdx.x >> 2;        // 4 channel-groups per batch
    const int c_base = (blockIdx.x & 3) << 8;  // 256 channels per block

    __shared__ int   s_idx[M];
    __shared__ float tile[2][M * PAD];

    const int t = threadIdx.x;
    if (t < M) s_idx[t] = idx[b * M + t];
    __syncthreads();

    const int f  = t & 15;    // float4 index within a 64-ch tile
    const int m0 = t >> 4;    // base token

    // Row base pointers for this thread's 4 gather rows (shared by all tiles).
    const float* wrow[4];
#pragma unroll
    for (int j = 0; j < 4; ++j)
        wrow[j] = w + (size_t)s_idx[m0 + (j << 4)] * C + c_base + (f << 2);

    float* const obase = out + (((size_t)b * C + c_base) << 6);

#define GATHER(ti, vv)                                            \
    _Pragma("unroll")                                             \
    for (int j = 0; j < 4; ++j)                                   \
        vv[j] = *(const fx4*)(wrow[j] + ((ti) << 6));

#define LDSWRITE(buf, vv)                                         \
    _Pragma("unroll")                                             \
    for (int j = 0; j < 4; ++j) {                                 \
        const int mm = m0 + (j << 4);                             \
        tile[buf][((f << 2) + 0) * PAD + mm] = vv[j].x;           \
        tile[buf][((f << 2) + 1) * PAD + mm] = vv[j].y;           \
        tile[buf][((f << 2) + 2) * PAD + mm] = vv[j].z;           \
        tile[buf][((f << 2) + 3) * PAD + mm] = vv[j].w;           \
    }

#define STORE(buf, ti)                                            \
    _Pragma("unroll")                                             \
    for (int j = 0; j < 4; ++j) {                                 \
        const int fo = (j << 8) + t;                              \
        const int cc = fo >> 4;                                   \
        const int mm = (fo & 15) << 2;                            \
        fx4 o;                                                    \
        o.x = tile[buf][cc * PAD + mm + 0];                       \
        o.y = tile[buf][cc * PAD + mm + 1];                       \
        o.z = tile[buf][cc * PAD + mm + 2];                       \
        o.w = tile[buf][cc * PAD + mm + 3];                       \
        __builtin_nontemporal_store(                              \
            o, (fx4*)(obase + ((ti) << 12) + (cc << 6) + mm));    \
    }

    // Prologue: tile 0 -> buf 0
    {
        fx4 v[4];
        GATHER(0, v);
        LDSWRITE(0, v);
    }
    __syncthreads();

    // Pipelined main loop: gathers for ti+1 overlap the store burst of ti.
    // Buffer separation makes one barrier per iteration sufficient:
    // STORE reads buf[ti&1] (written last iter, barrier-separated);
    // LDSWRITE fills buf[(ti+1)&1] (last read two phases ago).
#pragma unroll
    for (int ti = 0; ti < TILES - 1; ++ti) {
        fx4 v[4];
        GATHER(ti + 1, v);
        STORE(ti & 1, ti);
        LDSWRITE((ti + 1) & 1, v);
        __syncthreads();
    }

    // Epilogue: store last tile
    STORE((TILES - 1) & 1, TILES - 1);
}

extern "C" void kernel_launch(void* const* d_in, const int* in_sizes, int n_in,
                              void* d_out, int out_size, void* d_ws, size_t ws_size,
                              hipStream_t stream) {
    const int*   idx = (const int*)d_in[0];    // encoding_indices [256, 64]
    const float* w   = (const float*)d_in[1];  // weight [1024, 1024]
    float*       out = (float*)d_out;          // [256, 1024, 8, 8]

    dim3 grid(BS * TILES);  // 1024 blocks = 4/CU exactly, single round
    dim3 block(256);
    gather_transpose_kernel<<<grid, block, 0, stream>>>(idx, w, out);
}

// Round 4
// 79.854 us; speedup vs baseline: 1.0395x; 1.0395x over previous
//
#include <hip/hip_runtime.h>
#include <hip/hip_bf16.h>

// R4 CALIBRATION PROBE — NOT an optimization.
// out[b, c, m] = weight[idx[b, m], c]; correctness identical to R1/R2 kernel
// (both store passes write the same correct values).
//
// Purpose: three structurally different kernels all measured dur ~= 80-83 us.
// Two models: (A) kernel ~36 us at 1.9 TB/s writes (improvable, cause
// unknown), (B) kernel ~13 us at the 6.1 TB/s write floor, residual is
// harness fill(44us) + ~dozens of tiny reset() memset launches (~20 us).
// This probe doubles the HBM write traffic (two nt store passes, asm
// memory clobber between to block DSE; nt on both so pass 2 isn't absorbed
// as an L2 dirty-line hit). Delta dur = 67 MB / achieved write BW:
//   Model A -> +~35 us (dur >= ~105), kernel enters rocprof top-5.
//   Model B -> +~11 us (dur <= ~95) -> previous kernel was at roofline.

#define BS   256
#define M    64
#define C    1024
#define PAD  65   // 65 % 32 == 1 -> both LDS phases 2 lanes/bank = conflict-free

typedef float fx4 __attribute__((ext_vector_type(4)));

__global__ __launch_bounds__(256) void gather_transpose_kernel(
    const int* __restrict__ idx,      // [BS*M] int32
    const float* __restrict__ w,      // [NUM_EMB, C] fp32
    float* __restrict__ out)          // [BS, C, 8, 8] fp32
{
    const int b  = blockIdx.x >> 4;          // 16 channel-tiles per batch
    const int c0 = (blockIdx.x & 15) << 6;   // 64 channels per block

    __shared__ int   s_idx[M];
    __shared__ float tile[M * PAD];          // [cc][m], transposed

    const int t = threadIdx.x;
    if (t < M) s_idx[t] = idx[b * M + t];
    __syncthreads();

    // ---- load phase: gather rows, coalesced 256B per 16-lane group ----
    const int f = t & 15;                    // float4 index within the 64-ch slice
#pragma unroll
    for (int j = 0; j < 4; ++j) {
        const int m   = (t >> 4) + (j << 4); // token 0..63
        const int row = s_idx[m];
        const fx4 v = *(const fx4*)(w + row * C + c0 + (f << 2));
        tile[((f << 2) + 0) * PAD + m] = v.x;
        tile[((f << 2) + 1) * PAD + m] = v.y;
        tile[((f << 2) + 2) * PAD + m] = v.z;
        tile[((f << 2) + 3) * PAD + m] = v.w;
    }
    __syncthreads();

    // ---- store phase: TWO nt passes (calibration), 16 KiB contiguous ----
    float* obase = out + (((size_t)(b * C + c0)) << 6);
#pragma unroll
    for (int pass = 0; pass < 2; ++pass) {
#pragma unroll
        for (int j = 0; j < 4; ++j) {
            const int fo = (j << 8) + t;         // float4 slot 0..1023
            const int cc = fo >> 4;              // channel within tile
            const int m  = (fo & 15) << 2;       // token group of 4
            fx4 v;
            v.x = tile[cc * PAD + m + 0];
            v.y = tile[cc * PAD + m + 1];
            v.z = tile[cc * PAD + m + 2];
            v.w = tile[cc * PAD + m + 3];
            __builtin_nontemporal_store(v, (fx4*)(obase + (cc << 6) + m));
        }
        // Opaque memory clobber: pass-1 stores are observable -> no DSE.
        __asm__ __volatile__("" ::: "memory");
    }
}

extern "C" void kernel_launch(void* const* d_in, const int* in_sizes, int n_in,
                              void* d_out, int out_size, void* d_ws, size_t ws_size,
                              hipStream_t stream) {
    const int*   idx = (const int*)d_in[0];    // encoding_indices [256, 64]
    const float* w   = (const float*)d_in[1];  // weight [1024, 1024]
    float*       out = (float*)d_out;          // [256, 1024, 8, 8]

    dim3 grid(BS * (C / 64));  // 4096 blocks
    dim3 block(256);
    gather_transpose_kernel<<<grid, block, 0, stream>>>(idx, w, out);
}